// Round 10
// baseline (11730.541 us; speedup 1.0000x reference)
//
#include <hip/hip_runtime.h>
#include <hip/hip_bf16.h>
#include <math.h>

#define BB 256
#define LL 256
#define DD 4
#define HH 1024
#define SS 100
#define OUTD 3
#define X0 768          /* L*OUT */
#define K1 1792         /* 768 + 1024 */
#define K2 2048
#define NG 4096

typedef __attribute__((ext_vector_type(4))) float f32x4;
typedef __attribute__((ext_vector_type(8))) short bf16x8;
typedef __hip_bfloat16 bf16;

__device__ __forceinline__ float sigmoidf_(float x){ return 1.0f/(1.0f + __expf(-x)); }

// ---- two-level grid barrier: relaxed spin (r7 lesson: NO acquire in the
// poll loop), ONE threadfence release before arrive + ONE acquire after flip.
// With weights in LDS, the L2 inv this causes only refetches ~2.4MB of
// activations from L3 per step -- cheap.  16 groups x 16 blocks.
__device__ __forceinline__ void grid_barrier(unsigned* bar, int tid, int bid){
  asm volatile("s_waitcnt vmcnt(0)" ::: "memory");
  __syncthreads();
  if (tid == 0){
    unsigned* grp  = bar + (bid & 15) * 32;
    unsigned* root = bar + 512;
    unsigned* gen  = bar + 544;
    unsigned g = __hip_atomic_load(gen, __ATOMIC_RELAXED, __HIP_MEMORY_SCOPE_AGENT);
    __threadfence();                     // release: wb dirty L2 (activations)
    unsigned a = __hip_atomic_fetch_add(grp, 1u, __ATOMIC_RELAXED, __HIP_MEMORY_SCOPE_AGENT);
    bool flip = false;
    if (a == 15u){
      __hip_atomic_store(grp, 0u, __ATOMIC_RELAXED, __HIP_MEMORY_SCOPE_AGENT);
      unsigned r = __hip_atomic_fetch_add(root, 1u, __ATOMIC_RELAXED, __HIP_MEMORY_SCOPE_AGENT);
      if (r == 15u){
        __hip_atomic_store(root, 0u, __ATOMIC_RELAXED, __HIP_MEMORY_SCOPE_AGENT);
        __hip_atomic_store(gen, g + 1u, __ATOMIC_RELAXED, __HIP_MEMORY_SCOPE_AGENT);
        flip = true;
      }
    }
    if (!flip){
      while (__hip_atomic_load(gen, __ATOMIC_RELAXED, __HIP_MEMORY_SCOPE_AGENT) == g)
        __builtin_amdgcn_s_sleep(4);
    }
    __threadfence();                     // acquire: one inv -> fresh activations
  }
  __syncthreads();
}

struct PersistArgs {
  const bf16* W0r; const bf16* W1r; const bf16* Wl;
  const float* bias0; const float* bias1;
  float* c0; float* c1;
  bf16* xcat0; bf16* xcat1; bf16* x2_0; bf16* x2_1; bf16* th;
  const float* alphas; const float* betas; const float* barals; const float* snoise;
  float* prev; float* out;
  unsigned* bar;
};

// =====================================================================
// v10 cell phase: block owns 16 n'-cols (4 h-cols x 4 gates) of W in LDS.
// M=256 x N=16 x K GEMM: 8 waves x 32 rows (2 m-frags each), no split-K,
// no barriers in K-loop.  A via normal cached loads (L2 broadcast),
// B via swizzled ds_read from resident W.  Epilogue: 2-round LDS exchange
// (8KB scratch), LSTM pointwise with c-state IN REGISTERS.
// =====================================================================
template<int K, int KS, int WOFF, int WST, bool WTANH>
__device__ __forceinline__ void cell_v10(
    const bf16* __restrict__ Acat, char* __restrict__ smem,
    bf16* __restrict__ dstA, int ldA, int offA,
    bf16* __restrict__ dstB, int ldB, int offB,
    float cr[2], f32x4 bv,
    int b, int wave, int lr, int kq, int tid, int hcol)
{
  const bf16* aptr0 = Acat + (size_t)(wave*32 + lr) * K + kq*8;
  const bf16* aptr1 = aptr0 + (size_t)16 * K;
  const char* wbase = smem + WOFF + lr*WST;
  const int lsw = lr & 7;
  f32x4 acc0 = {}, acc1 = {};
  #pragma unroll
  for (int ks = 0; ks < KS; ks++){
    bf16x8 a0 = *(const bf16x8*)(aptr0 + ks*32);
    bf16x8 a1 = *(const bf16x8*)(aptr1 + ks*32);
    bf16x8 wv = *(const bf16x8*)(wbase + ((((ks*4) + kq) ^ lsw) << 4));
    acc0 = __builtin_amdgcn_mfma_f32_16x16x32_bf16(a0, wv, acc0, 0,0,0);
    acc1 = __builtin_amdgcn_mfma_f32_16x16x32_bf16(a1, wv, acc1, 0,0,0);
  }
  float* scratch = (float*)(smem + 122880);
  const int erow = tid >> 2, eh = tid & 3;
  #pragma unroll
  for (int rr = 0; rr < 2; rr++){
    if ((wave >> 2) == rr){
      #pragma unroll
      for (int j = 0; j < 4; j++){
        scratch[((wave&3)*32 +      kq*4 + j)*16 + lr] = acc0[j];
        scratch[((wave&3)*32 + 16 + kq*4 + j)*16 + lr] = acc1[j];
      }
    }
    __syncthreads();
    {
      f32x4 g = *(const f32x4*)&scratch[erow*16 + 4*eh];
      int row = rr*128 + erow;
      float gi = g[0] + bv[0];
      float gf = g[1] + bv[1];
      float gg = g[2] + bv[2];
      float go = g[3] + bv[3];
      float cn = sigmoidf_(gf)*cr[rr] + sigmoidf_(gi)*tanhf(gg);
      float hn = sigmoidf_(go)*tanhf(cn);
      cr[rr] = cn;
      dstA[(size_t)row*ldA + offA + hcol] = __float2bfloat16(hn);
      dstB[(size_t)row*ldB + offB + hcol] = __float2bfloat16(WTANH ? tanhf(hn) : hn);
    }
    __syncthreads();
  }
}

// ---- dec phase (blocks 0..95): 8 Wlin rows per block, read direct from L2
// (block-private, 16KB).  B-frag rows 8..15 duplicate rows 0..7 (cols 8..15
// of D discarded).  Diffusion epilogue; prev is block-local. ----
__device__ __forceinline__ void dec_v10(
    const PersistArgs& P, bf16* __restrict__ xn, char* __restrict__ smem,
    int b, int wave, int lr, int kq, int tid, int t)
{
  const bf16* aptr0 = P.th + (size_t)(wave*32 + lr) * HH + kq*8;
  const bf16* aptr1 = aptr0 + (size_t)16 * HH;
  const bf16* bptr  = P.Wl + (size_t)(8*b + (lr & 7)) * HH + kq*8;
  f32x4 acc0 = {}, acc1 = {};
  #pragma unroll
  for (int ks = 0; ks < 32; ks++){
    bf16x8 a0 = *(const bf16x8*)(aptr0 + ks*32);
    bf16x8 a1 = *(const bf16x8*)(aptr1 + ks*32);
    bf16x8 wv = *(const bf16x8*)(bptr + ks*32);
    acc0 = __builtin_amdgcn_mfma_f32_16x16x32_bf16(a0, wv, acc0, 0,0,0);
    acc1 = __builtin_amdgcn_mfma_f32_16x16x32_bf16(a1, wv, acc1, 0,0,0);
  }
  const int idxs = SS - t;
  float a = P.alphas[idxs], ba = P.barals[idxs], be = P.betas[idxs];
  float coef = (1.0f - a) / sqrtf(1.0f - ba);
  float isq  = 1.0f / sqrtf(a);
  float nf = (t+1 < SS) ? sqrtf(be) : 0.0f;
  float* outp = P.out + (size_t)(SS-1-t) * (BB*X0);
  float* scratch = (float*)(smem + 122880);
  #pragma unroll
  for (int rr = 0; rr < 2; rr++){
    if ((wave >> 2) == rr){
      #pragma unroll
      for (int j = 0; j < 4; j++){
        scratch[((wave&3)*32 +      kq*4 + j)*16 + lr] = acc0[j];
        scratch[((wave&3)*32 + 16 + kq*4 + j)*16 + lr] = acc1[j];
      }
    }
    __syncthreads();
    #pragma unroll
    for (int e = 0; e < 2; e++){
      int idx = tid*2 + e;                 // 128 rows x 8 cols
      int col = idx & 7, row_l = idx >> 3;
      int row = rr*128 + row_l, n = 8*b + col;
      float d = scratch[row_l*16 + col];
      float pv = P.prev[row*X0 + n];
      float dv = (pv - coef*d)*isq + nf*P.snoise[t*BB + row];
      outp[row*X0 + n] = dv;
      P.prev[row*X0 + n] = dv;
      xn[(size_t)row*K1 + n] = __float2bfloat16(dv);
    }
    __syncthreads();
  }
}

// =====================================================================
// persistent kernel: 256 blocks x 512 thr (1 block/CU, 2 waves/SIMD).
// LDS 128KiB: W0 slice [16][1792] @0 (57344B, swizzled), W1 slice
// [16][2048] @57344 (65536B), scratch 8KB @122880.  Weights loaded ONCE.
// =====================================================================
__global__ __launch_bounds__(512, 1) void persist(PersistArgs P)
{
  __shared__ __align__(16) char smem[131072];
  const int tid = threadIdx.x;
  const int wave = tid >> 6, lane = tid & 63;
  const int lr = lane & 15, kq = lane >> 4;
  const int b = blockIdx.x;

  // ---- one-time: W slices -> LDS (swizzled slot s -> s^(row&7)) ----
  for (int i = tid; i < 3584; i += 512){          // W0: 16 rows x 224 slots
    int row = i / 224, s = i % 224;
    bf16x8 v = *(const bf16x8*)(P.W0r + (size_t)(16*b + row)*K1 + s*8);
    *(bf16x8*)(smem + row*3584 + ((s ^ (row & 7)) << 4)) = v;
  }
  for (int i = tid; i < 4096; i += 512){          // W1: 16 rows x 256 slots
    int row = i >> 8, s = i & 255;
    bf16x8 v = *(const bf16x8*)(P.W1r + (size_t)(16*b + row)*K2 + s*8);
    *(bf16x8*)(smem + 57344 + row*4096 + ((s ^ (row & 7)) << 4)) = v;
  }

  // ---- fixed per-thread epilogue mapping; bias + c-state in registers ----
  const int erow = tid >> 2, eh = tid & 3;
  const int hcol = 4*b + eh;
  f32x4 b0v = *(const f32x4*)&P.bias0[16*b + 4*eh];
  f32x4 b1v = *(const f32x4*)&P.bias1[16*b + 4*eh];
  float c0r[2], c1r[2];
  #pragma unroll
  for (int rr = 0; rr < 2; rr++){
    int row = rr*128 + erow;
    c0r[rr] = P.c0[row*HH + hcol];
    c1r[rr] = P.c1[row*HH + hcol];
  }
  __syncthreads();

  for (int t = 1; t < SS; t++){
    bf16* xc  = (t & 1) ? P.xcat1 : P.xcat0;
    bf16* xn  = (t & 1) ? P.xcat0 : P.xcat1;
    bf16* x2c = (t & 1) ? P.x2_1 : P.x2_0;
    bf16* x2n = (t & 1) ? P.x2_0 : P.x2_1;

    cell_v10<K1, 56, 0, 3584, false>(xc, smem, x2c, K2, 0, xn, K1, X0,
                                     c0r, b0v, b, wave, lr, kq, tid, hcol);
    grid_barrier(P.bar, tid, b);
    cell_v10<K2, 64, 57344, 4096, true>(x2c, smem, x2n, K2, 1024, P.th, HH, 0,
                                        c1r, b1v, b, wave, lr, kq, tid, hcol);
    grid_barrier(P.bar, tid, b);
    if (b < 96)
      dec_v10(P, xn, smem, b, wave, lr, kq, tid, t);
    grid_barrier(P.bar, tid, b);
  }
}

// =====================================================================
// setup-phase helpers (unchanged from r9)
// =====================================================================
__device__ __forceinline__ void gemm32x32(const bf16* __restrict__ A, int lda,
                                          const bf16* __restrict__ W, int ldw,
                                          int m0, int wr0, int K,
                                          f32x4 acc[2][2], int lane)
{
  int r  = lane & 15;
  int kq = lane >> 4;
  const bf16* a0 = A + (size_t)(m0 + r)      * lda + kq*8;
  const bf16* a1 = A + (size_t)(m0 + 16 + r) * lda + kq*8;
  const bf16* b0 = W + (size_t)(wr0 + r)      * ldw + kq*8;
  const bf16* b1 = W + (size_t)(wr0 + 16 + r) * ldw + kq*8;
  for (int kk = 0; kk < K; kk += 32) {
    bf16x8 av0 = *(const bf16x8*)(a0 + kk);
    bf16x8 av1 = *(const bf16x8*)(a1 + kk);
    bf16x8 bv0 = *(const bf16x8*)(b0 + kk);
    bf16x8 bv1 = *(const bf16x8*)(b1 + kk);
    acc[0][0] = __builtin_amdgcn_mfma_f32_16x16x32_bf16(av0, bv0, acc[0][0], 0,0,0);
    acc[0][1] = __builtin_amdgcn_mfma_f32_16x16x32_bf16(av0, bv1, acc[0][1], 0,0,0);
    acc[1][0] = __builtin_amdgcn_mfma_f32_16x16x32_bf16(av1, bv0, acc[1][0], 0,0,0);
    acc[1][1] = __builtin_amdgcn_mfma_f32_16x16x32_bf16(av1, bv1, acc[1][1], 0,0,0);
  }
}

template<int EPI>
__global__ __launch_bounds__(256) void rgemm_kernel(
    const bf16* __restrict__ A, const bf16* __restrict__ W,
    const float* __restrict__ bias, const float* __restrict__ resid,
    bf16* __restrict__ d1, int ld1, bf16* __restrict__ d2, int ld2,
    float* __restrict__ f1, float* __restrict__ f2)
{
  int tid=threadIdx.x, wave=tid>>6, lane=tid&63;
  int m0 = blockIdx.x*32;
  int n0 = (blockIdx.y*4+wave)*32;
  f32x4 acc[2][2] = {};
  gemm32x32(A, HH, W, HH, m0, n0, HH, acc, lane);
  int cr=lane&15, rq=lane>>4;
  for (int r=0;r<2;r++) for (int c=0;c<2;c++) for (int j=0;j<4;j++) {
    int m = m0 + r*16+rq*4+j, n = n0 + c*16+cr;
    float v = acc[r][c][j] + bias[n];
    if (EPI==0) {
      float h = fmaxf(v,0.f) + resid[m*HH+n];
      d1[(size_t)m*ld1+n] = __float2bfloat16(h);
    } else if (EPI==1) {
      float tv = tanhf(v);
      if (n < HH) d1[(size_t)m*ld1+n] = __float2bfloat16(tv);
      else        d2[(size_t)m*ld2 + (n-HH)] = __float2bfloat16(tv);
    } else {
      float tv = tanhf(v);
      if (n < HH) f1[m*HH+n] = tv;
      else        f2[m*HH + (n-HH)] = tv;
    }
  }
}

// W rows interleaved: n' = col*4 + gate
__global__ void prep_w0_kernel(const float* __restrict__ Wih0, const float* __restrict__ Whh0,
                               bf16* __restrict__ W0r){
  int i = blockIdx.x*256 + threadIdx.x;
  if (i >= NG*K1) return;
  int np = i / K1, k = i % K1;
  int col = np >> 2, g = np & 3;
  int srow = g*HH + col;
  float v = (k < X0) ? Wih0[srow*X0 + k] : Whh0[srow*HH + (k - X0)];
  W0r[i] = __float2bfloat16(v);
}
__global__ void prep_w1_kernel(const float* __restrict__ Wih1, const float* __restrict__ Whh1,
                               bf16* __restrict__ W1r){
  int i = blockIdx.x*256 + threadIdx.x;
  if (i >= NG*K2) return;
  int np = i / K2, k = i % K2;
  int col = np >> 2, g = np & 3;
  int srow = g*HH + col;
  float v = (k < HH) ? Wih1[srow*HH + k] : Whh1[srow*HH + (k - HH)];
  W1r[i] = __float2bfloat16(v);
}
__global__ void cvt_kernel(const float* __restrict__ s, bf16* __restrict__ d, int n){
  int i = blockIdx.x*256 + threadIdx.x;
  if (i < n) d[i] = __float2bfloat16(s[i]);
}
__global__ void prep_bias_kernel(const float* bih0, const float* bhh0,
                                 const float* bih1, const float* bhh1,
                                 float* b0, float* b1, unsigned* bar){
  int i = blockIdx.x*256 + threadIdx.x;
  if (i < NG){
    int col = i >> 2, g = i & 3;
    int s = g*HH + col;
    b0[i] = bih0[s] + bhh0[s];
    b1[i] = bih1[s] + bhh1[s];
  }
  if (i < 1024) bar[i] = 0u;   // zero barrier state every call (replay-safe)
}
__global__ void init_x_kernel(const float* __restrict__ z, float* __restrict__ prev,
                              bf16* __restrict__ xcat1, float* __restrict__ out){
  int i = blockIdx.x*256 + threadIdx.x;
  if (i >= BB*X0) return;
  int m = i / X0, col = i % X0;
  int l = col / OUTD, d = col % OUTD;
  float v = z[(size_t)(m*LL + l)*DD + d];
  prev[i] = v;
  out[(size_t)(SS-1)*BB*X0 + i] = v;
  xcat1[(size_t)m*K1 + col] = __float2bfloat16(v);
}
__global__ void r1_kernel(const float* __restrict__ n0,
    const float* __restrict__ A1a, const float* __restrict__ b1a,
    const float* __restrict__ A1b, const float* __restrict__ b1b,
    float* __restrict__ h1fa, bf16* __restrict__ h1ba,
    float* __restrict__ h1fb, bf16* __restrict__ h1bb){
  int gid = blockIdx.x*256 + threadIdx.x;
  if (gid >= BB*2*HH) return;
  int m = gid >> 11;
  int col = gid & 2047;
  const float* A1; const float* b1; float* hf; bf16* hb; int c;
  if (col < HH){ A1=A1a; b1=b1a; hf=h1fa; hb=h1ba; c=col; }
  else         { A1=A1b; b1=b1b; hf=h1fb; hb=h1bb; c=col-HH; }
  float v = b1[c];
  for (int d=0; d<DD; d++) v += n0[m*DD + d] * A1[c*DD + d];
  v = fmaxf(v, 0.f);
  hf[m*HH + c] = v;
  hb[m*HH + c] = __float2bfloat16(v);
}

static inline size_t alup(size_t x){ return (x + 255) & ~(size_t)255; }

extern "C" void kernel_launch(void* const* d_in, const int* in_sizes, int n_in,
                              void* d_out, int out_size, void* d_ws, size_t ws_size,
                              hipStream_t stream) {
  const float* z      = (const float*)d_in[4];
  const float* n0     = (const float*)d_in[5];
  const float* snoise = (const float*)d_in[6];
  const float* alphas = (const float*)d_in[7];
  const float* betas  = (const float*)d_in[8];
  const float* barals = (const float*)d_in[9];
  const float* A1a = (const float*)d_in[10]; const float* b1a = (const float*)d_in[11];
  const float* A2a = (const float*)d_in[12]; const float* b2a = (const float*)d_in[13];
  const float* A3a = (const float*)d_in[14]; const float* b3a = (const float*)d_in[15];
  const float* A1b = (const float*)d_in[16]; const float* b1b = (const float*)d_in[17];
  const float* A2b = (const float*)d_in[18]; const float* b2b = (const float*)d_in[19];
  const float* A3b = (const float*)d_in[20]; const float* b3b = (const float*)d_in[21];
  const float* Wih0 = (const float*)d_in[22]; const float* Whh0 = (const float*)d_in[23];
  const float* bih0 = (const float*)d_in[24]; const float* bhh0 = (const float*)d_in[25];
  const float* Wih1 = (const float*)d_in[26]; const float* Whh1 = (const float*)d_in[27];
  const float* bih1 = (const float*)d_in[28]; const float* bhh1 = (const float*)d_in[29];
  const float* Wlin = (const float*)d_in[30];
  float* out = (float*)d_out;

  char* p = (char*)d_ws;
  size_t off = 0;
  auto take = [&](size_t bytes)->char*{ char* r = p + off; off = alup(off + bytes); return r; };
  bf16* W0cat = (bf16*)take((size_t)NG*K1*2);
  bf16* W1cat = (bf16*)take((size_t)NG*K2*2);
  bf16* WlinB = (bf16*)take((size_t)X0*HH*2);
  bf16* A2aB  = (bf16*)take((size_t)HH*HH*2);
  bf16* A2bB  = (bf16*)take((size_t)HH*HH*2);
  bf16* A3aB  = (bf16*)take((size_t)2*HH*HH*2);
  bf16* A3bB  = (bf16*)take((size_t)2*HH*HH*2);
  float* bias0 = (float*)take(NG*4);
  float* bias1 = (float*)take(NG*4);
  bf16* xcat0 = (bf16*)take((size_t)BB*K1*2);
  bf16* xcat1 = (bf16*)take((size_t)BB*K1*2);
  bf16* x2_0  = (bf16*)take((size_t)BB*K2*2);
  bf16* x2_1  = (bf16*)take((size_t)BB*K2*2);
  bf16* th    = (bf16*)take((size_t)BB*HH*2);
  float* c0   = (float*)take((size_t)BB*HH*4);
  float* c1   = (float*)take((size_t)BB*HH*4);
  float* prev = (float*)take((size_t)BB*X0*4);
  float* h1fa = (float*)take((size_t)BB*HH*4);
  float* h1fb = (float*)take((size_t)BB*HH*4);
  bf16* h1ba  = (bf16*)take((size_t)BB*HH*2);
  bf16* h1bb  = (bf16*)take((size_t)BB*HH*2);
  bf16* h2ba  = (bf16*)take((size_t)BB*HH*2);
  bf16* h2bb  = (bf16*)take((size_t)BB*HH*2);
  unsigned* bar = (unsigned*)take(4096);
  (void)ws_size; (void)in_sizes; (void)n_in; (void)out_size;

  prep_w0_kernel<<<(NG*K1+255)/256, 256, 0, stream>>>(Wih0, Whh0, W0cat);
  prep_w1_kernel<<<(NG*K2+255)/256, 256, 0, stream>>>(Wih1, Whh1, W1cat);
  cvt_kernel<<<(X0*HH+255)/256, 256, 0, stream>>>(Wlin, WlinB, X0*HH);
  cvt_kernel<<<(HH*HH+255)/256, 256, 0, stream>>>(A2a, A2aB, HH*HH);
  cvt_kernel<<<(HH*HH+255)/256, 256, 0, stream>>>(A2b, A2bB, HH*HH);
  cvt_kernel<<<(2*HH*HH+255)/256, 256, 0, stream>>>(A3a, A3aB, 2*HH*HH);
  cvt_kernel<<<(2*HH*HH+255)/256, 256, 0, stream>>>(A3b, A3bB, 2*HH*HH);
  prep_bias_kernel<<<(NG+255)/256, 256, 0, stream>>>(bih0, bhh0, bih1, bhh1, bias0, bias1, bar);
  init_x_kernel<<<(BB*X0+255)/256, 256, 0, stream>>>(z, prev, xcat1, out);
  r1_kernel<<<(BB*2*HH+255)/256, 256, 0, stream>>>(n0, A1a, b1a, A1b, b1b, h1fa, h1ba, h1fb, h1bb);
  rgemm_kernel<0><<<dim3(8,8), 256, 0, stream>>>(h1ba, A2aB, b2a, h1fa, h2ba, HH, nullptr, 0, nullptr, nullptr);
  rgemm_kernel<0><<<dim3(8,8), 256, 0, stream>>>(h1bb, A2bB, b2b, h1fb, h2bb, HH, nullptr, 0, nullptr, nullptr);
  rgemm_kernel<1><<<dim3(8,16), 256, 0, stream>>>(h2ba, A3aB, b3a, nullptr, xcat1 + X0, K1, x2_1 + HH, K2, nullptr, nullptr);
  rgemm_kernel<2><<<dim3(8,16), 256, 0, stream>>>(h2bb, A3bB, b3b, nullptr, nullptr, 0, nullptr, 0, c0, c1);

  PersistArgs pa;
  pa.W0r = W0cat; pa.W1r = W1cat; pa.Wl = WlinB;
  pa.bias0 = bias0; pa.bias1 = bias1;
  pa.c0 = c0; pa.c1 = c1;
  pa.xcat0 = xcat0; pa.xcat1 = xcat1; pa.x2_0 = x2_0; pa.x2_1 = x2_1; pa.th = th;
  pa.alphas = alphas; pa.betas = betas; pa.barals = barals; pa.snoise = snoise;
  pa.prev = prev; pa.out = out;
  pa.bar = bar;
  persist<<<256, 512, 0, stream>>>(pa);
}